// Round 2
// baseline (119.433 us; speedup 1.0000x reference)
//
#include <hip/hip_runtime.h>

#define NC 21
#define NB (NC * NC)      // 441 joint bins
#define NWAVES 8          // 512-thread blocks
#define HPAD 448          // per-wave histogram stride (multiple of 32 banks)
#define NBLK 1024         // hist grid: 4 blocks/CU on 256 CUs

__global__ void __launch_bounds__(512) hist_kernel(const int* __restrict__ pred,
                                                   const int* __restrict__ gt,
                                                   unsigned* __restrict__ partials,
                                                   int n) {
    __shared__ unsigned h[NWAVES][HPAD];
    const int tid = threadIdx.x;
    const int wave = tid >> 6;

    // zero LDS histograms
    #pragma unroll
    for (int i = tid; i < NWAVES * HPAD; i += 512) (&h[0][0])[i] = 0;
    __syncthreads();

    const int n4 = n >> 2;
    const int4* __restrict__ p4 = (const int4*)pred;
    const int4* __restrict__ g4 = (const int4*)gt;
    const int stride = gridDim.x * 512;
    int gidx = blockIdx.x * 512 + tid;

    for (int i = gidx; i < n4; i += stride) {
        int4 p = p4[i];
        int4 g = g4[i];
        atomicAdd(&h[wave][p.x + NC * g.x], 1u);
        atomicAdd(&h[wave][p.y + NC * g.y], 1u);
        atomicAdd(&h[wave][p.z + NC * g.z], 1u);
        atomicAdd(&h[wave][p.w + NC * g.w], 1u);
    }
    // scalar tail (n % 4 != 0) — no-op for this problem size
    for (int i = (n4 << 2) + gidx; i < n; i += stride) {
        atomicAdd(&h[wave][pred[i] + NC * gt[i]], 1u);
    }
    __syncthreads();

    // per-block partial: plain coalesced stores, no global atomics
    unsigned* out = partials + blockIdx.x * NB;
    for (int i = tid; i < NB; i += 512) {
        unsigned s = 0;
        #pragma unroll
        for (int w = 0; w < NWAVES; ++w) s += h[w][i];
        out[i] = s;
    }
}

__global__ void __launch_bounds__(512) reduce_miou(const unsigned* __restrict__ partials,
                                                   float* __restrict__ out) {
    __shared__ unsigned tot[NB];
    const int tid = threadIdx.x;

    if (tid < NB) {
        unsigned s = 0;
        #pragma unroll 8
        for (int k = 0; k < NBLK; ++k) s += partials[k * NB + tid];
        tot[tid] = s;
    }
    __syncthreads();

    float iou = 0.0f;
    if (tid < NC) {
        float pc = 0.0f, gc = 0.0f;
        #pragma unroll
        for (int g = 0; g < NC; ++g) pc += (float)tot[tid + NC * g];   // pred_counts[tid]
        #pragma unroll
        for (int p = 0; p < NC; ++p) gc += (float)tot[p + NC * tid];   // gt_counts[tid]
        float inter = (float)tot[tid * (NC + 1)];                      // diagonal
        float uni = pc + gc - inter;
        iou = (inter + 1e-7f) / (uni + 1e-7f);
    }
    // reduce the 21 lane values within wave 0 (lanes >= 21 are 0; waves > 0 skip)
    if (tid < 64) {
        for (int off = 32; off; off >>= 1) iou += __shfl_down(iou, off);
        if (tid == 0) out[0] = iou * (1.0f / 21.0f);
    }
}

extern "C" void kernel_launch(void* const* d_in, const int* in_sizes, int n_in,
                              void* d_out, int out_size, void* d_ws, size_t ws_size,
                              hipStream_t stream) {
    const int* pred = (const int*)d_in[0];
    const int* gt   = (const int*)d_in[1];
    unsigned* partials = (unsigned*)d_ws;   // NBLK * NB * 4 = 1.8 MB, fully overwritten
    float* out = (float*)d_out;
    const int n = in_sizes[0];

    hist_kernel<<<NBLK, 512, 0, stream>>>(pred, gt, partials, n);
    reduce_miou<<<1, 512, 0, stream>>>(partials, out);
}

// Round 3
// 98.266 us; speedup vs baseline: 1.2154x; 1.2154x over previous
//
#include <hip/hip_runtime.h>

#define NC 21
#define NB (NC * NC)      // 441 joint bins
#define NWAVES 8          // 512-thread blocks
#define HPAD 448          // per-wave histogram stride
#define NBLK 512
#define NTHR 512
#define UNROLL 8          // int4s per array per thread per round

__global__ void __launch_bounds__(NTHR) zero_hist(unsigned* __restrict__ h) {
    int i = threadIdx.x;
    if (i < NB) h[i] = 0u;
}

__global__ void __launch_bounds__(NTHR) hist_kernel(const int* __restrict__ pred,
                                                    const int* __restrict__ gt,
                                                    unsigned* __restrict__ g_hist,
                                                    int n) {
    __shared__ unsigned h[NWAVES][HPAD];
    const int tid = threadIdx.x;
    const int wave = tid >> 6;

    #pragma unroll
    for (int i = tid; i < NWAVES * HPAD; i += NTHR) (&h[0][0])[i] = 0u;
    __syncthreads();

    const int n4 = n >> 2;
    const int4* __restrict__ p4 = (const int4*)pred;
    const int4* __restrict__ g4 = (const int4*)gt;
    const int stride = NBLK * NTHR;
    const int gidx = (int)blockIdx.x * NTHR + tid;

    int base = gidx;
    // Full rounds: issue ALL 16 independent 16B loads before any consumer.
    // This is the Little's-law fix: 256 B/lane in flight instead of 32 B.
    for (; base + (UNROLL - 1) * stride < n4; base += UNROLL * stride) {
        int4 pv[UNROLL], gv[UNROLL];
        #pragma unroll
        for (int k = 0; k < UNROLL; ++k) pv[k] = p4[base + k * stride];
        #pragma unroll
        for (int k = 0; k < UNROLL; ++k) gv[k] = g4[base + k * stride];
        #pragma unroll
        for (int k = 0; k < UNROLL; ++k) {
            atomicAdd(&h[wave][pv[k].x + NC * gv[k].x], 1u);
            atomicAdd(&h[wave][pv[k].y + NC * gv[k].y], 1u);
            atomicAdd(&h[wave][pv[k].z + NC * gv[k].z], 1u);
            atomicAdd(&h[wave][pv[k].w + NC * gv[k].w], 1u);
        }
    }
    // leftover int4s (not hit at this problem size: n4 == 8*stride exactly)
    for (; base < n4; base += stride) {
        int4 p = p4[base], g = g4[base];
        atomicAdd(&h[wave][p.x + NC * g.x], 1u);
        atomicAdd(&h[wave][p.y + NC * g.y], 1u);
        atomicAdd(&h[wave][p.z + NC * g.z], 1u);
        atomicAdd(&h[wave][p.w + NC * g.w], 1u);
    }
    // scalar tail (n % 4)
    for (int i = (n4 << 2) + gidx; i < n; i += stride) {
        atomicAdd(&h[wave][pred[i] + NC * gt[i]], 1u);
    }

    __syncthreads();
    // per-block reduce -> one global atomic per bin per block
    for (int i = tid; i < NB; i += NTHR) {
        unsigned s = 0;
        #pragma unroll
        for (int w = 0; w < NWAVES; ++w) s += h[w][i];
        if (s) atomicAdd(&g_hist[i], s);
    }
}

__global__ void __launch_bounds__(64) miou_final(const unsigned* __restrict__ hist,
                                                 float* __restrict__ out) {
    const int lane = threadIdx.x;
    float iou = 0.0f;
    if (lane < NC) {
        float pc = 0.0f, gc = 0.0f;
        #pragma unroll
        for (int g = 0; g < NC; ++g) pc += (float)hist[lane + NC * g];   // pred_counts
        #pragma unroll
        for (int p = 0; p < NC; ++p) gc += (float)hist[p + NC * lane];   // gt_counts
        float inter = (float)hist[lane * (NC + 1)];                      // diagonal
        float uni = pc + gc - inter;
        iou = (inter + 1e-7f) / (uni + 1e-7f);
    }
    for (int off = 32; off; off >>= 1) iou += __shfl_down(iou, off);
    if (lane == 0) out[0] = iou * (1.0f / 21.0f);
}

extern "C" void kernel_launch(void* const* d_in, const int* in_sizes, int n_in,
                              void* d_out, int out_size, void* d_ws, size_t ws_size,
                              hipStream_t stream) {
    const int* pred = (const int*)d_in[0];
    const int* gt   = (const int*)d_in[1];
    unsigned* g_hist = (unsigned*)d_ws;
    float* out = (float*)d_out;
    const int n = in_sizes[0];

    zero_hist<<<1, NTHR, 0, stream>>>(g_hist);
    hist_kernel<<<NBLK, NTHR, 0, stream>>>(pred, gt, g_hist, n);
    miou_final<<<1, 64, 0, stream>>>(g_hist, out);
}